// Round 13
// baseline (336.780 us; speedup 1.0000x reference)
//
#include <hip/hip_runtime.h>
#include <math.h>

// DigitCaps dynamic routing. B=512, I=1152, K=8, C=10, D=16, 3 iters.
//
// R5 structure: materialize bf16 u_hat (189 MB) in ws; each routing pass
// streams it once; softmax fully in-register.
// R7/R16/R17: producer at (256,4) settles at 64 VGPR; extra live state
//   SPILLS (b-oct, double-buffer, sched_barrier-pinned prefetch). Producer
//   pipelining is a DEAD END; keep R15 verbatim (124-136us).
// R10: i-splitting doubles s0 atomics. R12: b-pairs double W_t loads.
// R14 WIN (311): route6 = cd-quad route (VGPR ~20) + grid 2048 + rcp.
// R15 WIN (302): producer LDS cross-wave reduce (atomics /4), K1_CH 64.
// R18 WIN (291): squash fused into route prologue (quad-local squash4).
// R19 (this round): route streams at only ~2.9 TB/s; outstanding-bytes are
//   ample, so theory = TRANSACTION WIDTH (ushort4 = 320 B/wave-load, 2.5
//   lines). route8 stages 8-row groups (2560 B) into wave-private LDS via
//   3x global_load_lds width-16 (full 1 KB transactions), then reads the
//   40-lane x 8 B pattern from LDS. vmcnt(0)+sched_barrier per group
//   (rule #18). Falsifier: route >= 65us => width wasn't the limit.

#define UHQ 40          // ushort4 quads per (b,i) row (160 bf16 elems)
#define K1_CH 64        // producer i-chunks (18 i each), 4 b per wave

__device__ __forceinline__ float dot8(const float4 w0, const float4 w1,
                                      const float4 ua, const float4 ub) {
    return w0.x*ua.x + w0.y*ua.y + w0.z*ua.z + w0.w*ua.w
         + w1.x*ub.x + w1.y*ub.y + w1.z*ub.z + w1.w*ub.w;
}

__device__ __forceinline__ unsigned short bf16_rn(float x) {
    unsigned u = __float_as_uint(x);
    u += 0x7FFFu + ((u >> 16) & 1u);
    return (unsigned short)(u >> 16);
}
__device__ __forceinline__ float bf16_to_f(unsigned short h) {
    return __uint_as_float(((unsigned)h) << 16);
}

// quad-local squash: lane q holds 4 of the 16 dims of class c=q>>2; the
// 4 lanes of the quad group hold all 16. ns via shfl_xor{1,2}.
__device__ __forceinline__ float4 squash4(float4 x) {
    float ns = x.x*x.x + x.y*x.y + x.z*x.z + x.w*x.w;
    ns += __shfl_xor(ns, 1);
    ns += __shfl_xor(ns, 2);
    const float sc = ns * __builtin_amdgcn_rcpf((1.0f + ns) * (sqrtf(ns) + 1e-8f));
    return make_float4(x.x*sc, x.y*sc, x.z*sc, x.w*sc);
}

// ---------------- W transpose: W[i][c][d][k] -> W_t[i][j][q] (float4 units) ----------------
__global__ void transpose_W(const float4* __restrict__ W4, float4* __restrict__ Wt4)
{
    int tid = blockIdx.x * 256 + threadIdx.x;
    if (tid >= 1152 * 320) return;
    int i = tid / 320, r = tid - i * 320;
    int q = r >> 3, j = r & 7;
    Wt4[i * 320 + j * 40 + q] = W4[tid];   // read coalesced, scatter within 5 KB row
}

// ---------------- Producer (R15 VERBATIM): u_hat bf16 + fused pass-0 sum, LDS reduce ----------------
// K1_CH 64 -> 18 i/wave, 8192 waves, grid 2048 = 8 blocks/CU (VGPR 64 tier),
// one uniform round. Block's 4 waves share the b-quad: waves 1-3 park acc in
// LDS, wave 0 alone issues atomics. DO NOT add prefetch/double-buffer.
__global__ __launch_bounds__(256, 4)
void produce_uhat_t(const float* __restrict__ u, const float* __restrict__ Wt,
                    unsigned short* __restrict__ uhat_h, float* __restrict__ s0)
{
    const int t = threadIdx.x, lane = t & 63, wv = t >> 6;
    const int gid = blockIdx.x * 4 + wv;
    const int bq  = gid / K1_CH;          // 0..127 (same for all 4 waves of a block)
    const int ch  = gid - bq * K1_CH;     // 0..63
    const int b0  = bq * 4;
    const int i0  = ch * 18;
    const int q   = lane;
    const bool act = (q < UHQ);

    __shared__ float4 red[480];           // 3 waves x 40 lanes x 4 float4 = 7680 B

    float4 acc[4];
    #pragma unroll
    for (int bb = 0; bb < 4; ++bb) acc[bb] = make_float4(0.f, 0.f, 0.f, 0.f);

    for (int ii = 0; ii < 18; ++ii) {
        const int i = i0 + ii;
        float4 w4[8];
        if (act) {
            const float4* wb = (const float4*)(Wt + (size_t)i * 1280);
            #pragma unroll
            for (int j = 0; j < 8; ++j) w4[j] = wb[j * 40 + q];   // 640 B contiguous
        }
        #pragma unroll
        for (int bb = 0; bb < 4; ++bb) {
            const int b = b0 + bb;
            const float4* up = (const float4*)(u + ((size_t)b * 1152 + i) * 8);
            const float4 ua = up[0], ub = up[1];   // wave-uniform broadcast
            if (act) {
                float4 uh;
                uh.x = dot8(w4[0], w4[1], ua, ub);
                uh.y = dot8(w4[2], w4[3], ua, ub);
                uh.z = dot8(w4[4], w4[5], ua, ub);
                uh.w = dot8(w4[6], w4[7], ua, ub);
                acc[bb].x += uh.x; acc[bb].y += uh.y;
                acc[bb].z += uh.z; acc[bb].w += uh.w;
                ushort4 h;
                h.x = bf16_rn(uh.x); h.y = bf16_rn(uh.y);
                h.z = bf16_rn(uh.z); h.w = bf16_rn(uh.w);
                ((ushort4*)uhat_h)[((size_t)b * 1152 + i) * UHQ + q] = h;
            }
        }
    }

    // cross-wave reduction of the pass-0 partial sums
    if (wv > 0 && act) {
        float4* rp = red + ((wv - 1) * 40 + q) * 4;
        rp[0] = acc[0]; rp[1] = acc[1]; rp[2] = acc[2]; rp[3] = acc[3];
    }
    __syncthreads();
    if (wv == 0 && act) {
        #pragma unroll
        for (int w = 0; w < 3; ++w) {
            const float4* rp = red + (w * 40 + q) * 4;
            #pragma unroll
            for (int bb = 0; bb < 4; ++bb) {
                const float4 r = rp[bb];
                acc[bb].x += r.x; acc[bb].y += r.y;
                acc[bb].z += r.z; acc[bb].w += r.w;
            }
        }
#if defined(__HIP_DEVICE_COMPILE__)
        #pragma unroll
        for (int bb = 0; bb < 4; ++bb) {
            float* sp = s0 + (size_t)(b0 + bb) * 160 + q * 4;
            unsafeAtomicAdd(sp + 0, acc[bb].x);
            unsafeAtomicAdd(sp + 1, acc[bb].y);
            unsafeAtomicAdd(sp + 2, acc[bb].z);
            unsafeAtomicAdd(sp + 3, acc[bb].w);
        }
#endif
    }
}

// ---------------- Producer fallback (divergent W, no W_t buffer; R9 geometry) ----------------
__global__ __launch_bounds__(256, 4)
void produce_uhat_div(const float* __restrict__ u, const float* __restrict__ W,
                      unsigned short* __restrict__ uhat_h, float* __restrict__ s0)
{
    const int t = threadIdx.x, lane = t & 63, wv = t >> 6;
    const int gid = blockIdx.x * 4 + wv;
    const int bq  = gid / 32;
    const int ch  = gid - bq * 32;
    const int b0  = bq * 4;
    const int i0  = ch * 36;
    const int q   = lane;
    const bool act = (q < UHQ);

    float4 acc[4];
    #pragma unroll
    for (int bb = 0; bb < 4; ++bb) acc[bb] = make_float4(0.f, 0.f, 0.f, 0.f);

    for (int ii = 0; ii < 36; ++ii) {
        const int i = i0 + ii;
        float4 w4[8];
        if (act) {
            const float4* wp = (const float4*)(W + (size_t)i * 1280 + q * 32);
            #pragma unroll
            for (int j = 0; j < 8; ++j) w4[j] = wp[j];
        }
        #pragma unroll
        for (int bb = 0; bb < 4; ++bb) {
            const int b = b0 + bb;
            const float4* up = (const float4*)(u + ((size_t)b * 1152 + i) * 8);
            const float4 ua = up[0], ub = up[1];
            if (act) {
                float4 uh;
                uh.x = dot8(w4[0], w4[1], ua, ub);
                uh.y = dot8(w4[2], w4[3], ua, ub);
                uh.z = dot8(w4[4], w4[5], ua, ub);
                uh.w = dot8(w4[6], w4[7], ua, ub);
                acc[bb].x += uh.x; acc[bb].y += uh.y;
                acc[bb].z += uh.z; acc[bb].w += uh.w;
                ushort4 h;
                h.x = bf16_rn(uh.x); h.y = bf16_rn(uh.y);
                h.z = bf16_rn(uh.z); h.w = bf16_rn(uh.w);
                ((ushort4*)uhat_h)[((size_t)b * 1152 + i) * UHQ + q] = h;
            }
        }
    }
    if (act) {
#if defined(__HIP_DEVICE_COMPILE__)
        #pragma unroll
        for (int bb = 0; bb < 4; ++bb) {
            float* sp = s0 + (size_t)(b0 + bb) * 160 + q * 4;
            unsafeAtomicAdd(sp + 0, acc[bb].x);
            unsafeAtomicAdd(sp + 1, acc[bb].y);
            unsafeAtomicAdd(sp + 2, acc[bb].z);
            unsafeAtomicAdd(sp + 3, acc[bb].w);
        }
#endif
    }
}

// ---------------- Routing pass v8: LDS width-staged stream + inline squash ----------------
// Wave owns (b, i-chunk of 72); lane q = cd-quad (40/64 active). Per 8-row
// group (2560 B): 3x global_load_lds width-16 (full 1 KB wave transactions)
// into a wave-private LDS buffer, vmcnt(0)+sched_barrier, then ds_read_b64
// the 40-lane x 8 B pattern. Softmax identical to route6. 10 KB LDS/block.
template <int PASS>
__global__ __launch_bounds__(256, 8)
void route8(const unsigned short* __restrict__ uhat_h,
            const float* __restrict__ s0g, const float* __restrict__ s1g,
            float* __restrict__ sg)
{
    const int t = threadIdx.x, lane = t & 63, wv = t >> 6;
    const int gid = blockIdx.x * 4 + wv;
    const int b   = gid >> 4;             // 0..511
    const int ch  = gid & 15;             // 0..15
    const int i0  = ch * 72;
    const int q   = lane;
    const bool act = (q < UHQ);

    __shared__ uint4 stage[4][160];       // per-wave 8-row buffer (2560 B each)
    uint4* st = &stage[wv][0];
    const char* stc = (const char*)st;

    // inline squash prologue (once per wave; all lanes run the shfls)
    float4 va;
    {
        float4 x0 = make_float4(0.f, 0.f, 0.f, 0.f);
        if (act) x0 = ((const float4*)s0g)[(size_t)b * UHQ + q];
        x0.x *= 0.1f; x0.y *= 0.1f; x0.z *= 0.1f; x0.w *= 0.1f;
        va = squash4(x0);
        if (PASS == 2) {
            float4 x1 = make_float4(0.f, 0.f, 0.f, 0.f);
            if (act) x1 = ((const float4*)s1g)[(size_t)b * UHQ + q];
            const float4 v1 = squash4(x1);
            va.x += v1.x; va.y += v1.y; va.z += v1.z; va.w += v1.w;
        }
    }
    float4 sacc = make_float4(0.f, 0.f, 0.f, 0.f);

    const uint4* ubase = (const uint4*)uhat_h;   // 16 B units; 20 per row

    #pragma unroll 1
    for (int g = 0; g < 9; ++g) {
        // ---- stage 8 rows (160 uint4 = 2560 B) into wave-private LDS ----
        const uint4* src = ubase + ((size_t)b * 1152 + i0 + g * 8) * 20;
        // previous group's ds_reads fully consumed by compute (compiler
        // waits before use); drain lgkm to be safe before overwriting.
        asm volatile("s_waitcnt lgkmcnt(0)" ::: "memory");
        __builtin_amdgcn_global_load_lds(src + lane,        st,        16, 0, 0);
        __builtin_amdgcn_global_load_lds(src + 64 + lane,   st + 64,   16, 0, 0);
        if (lane < 32)
            __builtin_amdgcn_global_load_lds(src + 128 + lane, st + 128, 16, 0, 0);
        asm volatile("s_waitcnt vmcnt(0)" ::: "memory");
        __builtin_amdgcn_sched_barrier(0);   // rule #18: no hoist past the wait

        #pragma unroll
        for (int r = 0; r < 8; r += 2) {
            float4 uh0 = make_float4(0.f, 0.f, 0.f, 0.f);
            float4 uh1 = make_float4(0.f, 0.f, 0.f, 0.f);
            if (act) {
                const ushort4 h0 = *(const ushort4*)(stc + r * 320 + q * 8);
                const ushort4 h1 = *(const ushort4*)(stc + (r + 1) * 320 + q * 8);
                uh0.x = bf16_to_f(h0.x); uh0.y = bf16_to_f(h0.y);
                uh0.z = bf16_to_f(h0.z); uh0.w = bf16_to_f(h0.w);
                uh1.x = bf16_to_f(h1.x); uh1.y = bf16_to_f(h1.y);
                uh1.z = bf16_to_f(h1.z); uh1.w = bf16_to_f(h1.w);
            }
            // per-c logit: 4-lane segmented reduction (two independent chains)
            float p0 = uh0.x*va.x + uh0.y*va.y + uh0.z*va.z + uh0.w*va.w;
            float p1 = uh1.x*va.x + uh1.y*va.y + uh1.z*va.z + uh1.w*va.w;
            p0 += __shfl_xor(p0, 1);  p1 += __shfl_xor(p1, 1);
            p0 += __shfl_xor(p0, 2);  p1 += __shfl_xor(p1, 2);
            // softmax, no max-subtraction (|logit| < ~0.5); mask inactive lanes
            const float e0 = act ? __expf(p0) : 0.0f;
            const float e1 = act ? __expf(p1) : 0.0f;
            float s0v = e0, s1v = e1;
            // xor-butterfly strides 4..32: every lane gets the 10-class sum
            s0v += __shfl_xor(s0v, 4);   s1v += __shfl_xor(s1v, 4);
            s0v += __shfl_xor(s0v, 8);   s1v += __shfl_xor(s1v, 8);
            s0v += __shfl_xor(s0v, 16);  s1v += __shfl_xor(s1v, 16);
            s0v += __shfl_xor(s0v, 32);  s1v += __shfl_xor(s1v, 32);
            const float c0 = e0 * __builtin_amdgcn_rcpf(s0v);
            const float c1 = e1 * __builtin_amdgcn_rcpf(s1v);
            sacc.x += c0 * uh0.x + c1 * uh1.x;
            sacc.y += c0 * uh0.y + c1 * uh1.y;
            sacc.z += c0 * uh0.z + c1 * uh1.z;
            sacc.w += c0 * uh0.w + c1 * uh1.w;
        }
    }
    if (act) {
#if defined(__HIP_DEVICE_COMPILE__)
        float* sp = sg + (size_t)b * 160 + q * 4;
        unsafeAtomicAdd(sp + 0, sacc.x);
        unsafeAtomicAdd(sp + 1, sacc.y);
        unsafeAtomicAdd(sp + 2, sacc.z);
        unsafeAtomicAdd(sp + 3, sacc.w);
#endif
    }
}

// ---------------- squash with pre-scale (final output only) ----------------
__global__ void squash_scale(const float* __restrict__ s, float* __restrict__ vout,
                             float scale)
{
    int r = blockIdx.x * 256 + threadIdx.x;
    if (r >= 512 * 10) return;
    const float* sp = s + (size_t)r * 16;
    float sv[16];
    float ns = 0.0f;
    #pragma unroll
    for (int d = 0; d < 16; ++d) {
        float x = sp[d] * scale;
        sv[d] = x;
        ns += x * x;
    }
    float sc = ns / ((1.0f + ns) * (sqrtf(ns) + 1e-8f));
    float* o = vout + (size_t)r * 16;
    #pragma unroll
    for (int d = 0; d < 16; ++d) o[d] = sv[d] * sc;
}

// ---------------- tiny-ws fallback (R3-style): thread owns (b,c) ----------------
template <int PASS>
__global__ __launch_bounds__(256, 4)
void pass_fb(const float* __restrict__ u, const float* __restrict__ W,
             const float* __restrict__ v0g, const float* __restrict__ v1g,
             float* __restrict__ s_atomic)
{
    const int t    = threadIdx.x;
    const int lane = t & 63;
    const int wv   = t >> 6;
    const int bsub = lane / 10;
    const int c    = lane - bsub * 10;
    const bool lane_ok = (bsub < 6);
    const int b    = blockIdx.y * 24 + wv * 6 + bsub;
    const bool valid = lane_ok && (b < 512);
    const int bc   = valid ? b : 511;
    const int base = lane_ok ? bsub * 10 : 0;
    const int i0   = blockIdx.x * 24;

    float v[16];
    #pragma unroll
    for (int d = 0; d < 16; ++d) v[d] = 0.0f;
    if (PASS >= 1) {
        const float* vp = v0g + ((size_t)bc * 10 + c) * 16;
        #pragma unroll
        for (int d = 0; d < 16; ++d) v[d] = vp[d];
        if (PASS >= 2) {
            const float* vq = v1g + ((size_t)bc * 10 + c) * 16;
            #pragma unroll
            for (int d = 0; d < 16; ++d) v[d] += vq[d];
        }
    }

    float s_acc[16];
    #pragma unroll
    for (int d = 0; d < 16; ++d) s_acc[d] = 0.0f;

    for (int ii = 0; ii < 24; ++ii) {
        const int i = i0 + ii;
        const float4* up = (const float4*)(u + ((size_t)bc * 1152 + i) * 8);
        const float4 ua = up[0];
        const float4 ub = up[1];
        const float* Wp = W + ((size_t)i * 10 + c) * 128;

        float h[16];
        #pragma unroll
        for (int d = 0; d < 16; ++d) {
            const float4* wp = (const float4*)(Wp + d * 8);
            h[d] = dot8(wp[0], wp[1], ua, ub);
        }

        if (PASS == 0) {
            #pragma unroll
            for (int d = 0; d < 16; ++d) s_acc[d] += h[d];
        } else {
            float lg = 0.0f;
            #pragma unroll
            for (int d = 0; d < 16; ++d) lg += h[d] * v[d];
            float lj[10];
            #pragma unroll
            for (int j = 0; j < 10; ++j) lj[j] = __shfl(lg, base + j);
            float m = lj[0];
            #pragma unroll
            for (int j = 1; j < 10; ++j) m = fmaxf(m, lj[j]);
            float sum = 0.0f;
            #pragma unroll
            for (int j = 0; j < 10; ++j) sum += __expf(lj[j] - m);
            const float coef = __expf(lg - m) / sum;
            #pragma unroll
            for (int d = 0; d < 16; ++d) s_acc[d] += coef * h[d];
        }
    }
    if (PASS == 0) {
        #pragma unroll
        for (int d = 0; d < 16; ++d) s_acc[d] *= 0.1f;
    }
    if (valid) {
#if defined(__HIP_DEVICE_COMPILE__)
        #pragma unroll
        for (int d = 0; d < 16; ++d)
            unsafeAtomicAdd(&s_atomic[((size_t)b * 10 + c) * 16 + d], s_acc[d]);
#endif
    }
}

extern "C" void kernel_launch(void* const* d_in, const int* in_sizes, int n_in,
                              void* d_out, int out_size, void* d_ws, size_t ws_size,
                              hipStream_t stream)
{
    const float* u = (const float*)d_in[0];   // [512,1152,8]
    const float* W = (const float*)d_in[1];   // [1152,10,16,8]
    float* out = (float*)d_out;               // [512,10,16]

    float* v0 = (float*)d_ws;
    float* v1 = v0 + 81920;
    float* s0 = v1 + 81920;
    float* s1 = s0 + 81920;
    float* s2 = s1 + 81920;
    float* wt = s2 + 81920;                   // 1,474,560 f32 (5.9 MB)

    const size_t head   = (size_t)5 * 81920 * sizeof(float);          // 1.64 MB
    const size_t wtsz   = (size_t)1152 * 1280 * sizeof(float);        // 5.90 MB
    const size_t uh_b16 = (size_t)512 * 1152 * 160 * 2;               // 188.7 MB

    hipMemsetAsync(s0, 0, (size_t)3 * 81920 * sizeof(float), stream);

    dim3 blk(256);

    if (ws_size >= head + wtsz + uh_b16) {
        unsigned short* uhh = (unsigned short*)(wt + 1152 * 1280);
        transpose_W<<<1440, blk, 0, stream>>>((const float4*)W, (float4*)wt);
        produce_uhat_t<<<2048, blk, 0, stream>>>(u, wt, uhh, s0);
        route8<1><<<2048, blk, 0, stream>>>(uhh, s0, nullptr, s1);
        route8<2><<<2048, blk, 0, stream>>>(uhh, s0, s1, s2);
        squash_scale<<<20, blk, 0, stream>>>(s2, out, 1.0f);
    } else if (ws_size >= head + uh_b16) {
        unsigned short* uhh = (unsigned short*)wt;   // no W_t buffer
        produce_uhat_div<<<1024, blk, 0, stream>>>(u, W, uhh, s0);
        route8<1><<<2048, blk, 0, stream>>>(uhh, s0, nullptr, s1);
        route8<2><<<2048, blk, 0, stream>>>(uhh, s0, s1, s2);
        squash_scale<<<20, blk, 0, stream>>>(s2, out, 1.0f);
    } else {
        dim3 grid(48, 22);
        pass_fb<0><<<grid, blk, 0, stream>>>(u, W, nullptr, nullptr, s0);
        squash_scale<<<20, blk, 0, stream>>>(s0, v0, 1.0f);
        pass_fb<1><<<grid, blk, 0, stream>>>(u, W, v0, nullptr, s1);
        squash_scale<<<20, blk, 0, stream>>>(s1, v1, 1.0f);
        pass_fb<2><<<grid, blk, 0, stream>>>(u, W, v0, v1, s2);
        squash_scale<<<20, blk, 0, stream>>>(s2, out, 1.0f);
    }
}

// Round 14
// 295.586 us; speedup vs baseline: 1.1394x; 1.1394x over previous
//
#include <hip/hip_runtime.h>
#include <math.h>

// DigitCaps dynamic routing. B=512, I=1152, K=8, C=10, D=16, 3 iters.
//
// FINAL (R20) = R18 verbatim, the measured best (291.0 us). Session ledger:
// R5 structure: materialize bf16 u_hat (189 MB) in ws; each routing pass
//   streams it once; softmax fully in-register.
// Producer dead-ends (5/5 failed): ILP prefetch folded (R11); forced
//   launch_bounds spills (R7); b-oct spills + red[] 32-way conflicts (R16);
//   sched_barrier pins spilling loads, FETCH 16->177 MB (R17); b-pairs double
//   W_t loads (R12). Producer is latency-bound at 64 VGPR, 124-137us, with
//   FETCH already minimal (16 MB). KEEP VERBATIM.
// Route dead-ends (4/4 failed since route6): c-lane layouts >=80 VGPR lose
//   the 8-wave tier (R13); 4-wide unroll = no gain (R16); global_load_lds
//   width-staging loses L3 residency + vmcnt(0) drain serializes (R19:
//   163us/pass, VALUBusy 2.5%). route6s ~67us is the equilibrium.
// Structural wins: R14 route TLP (cd-quad VGPR~20, grid 2048 = 8 blocks/CU);
//   R15 LDS cross-wave reduce (atomics /4, WRITE 226->206 MB); R18 squash
//   fused into route prologue (quad-local squash4, -2 launches).

#define UHQ 40          // ushort4 quads per (b,i) row (160 bf16 elems)
#define K1_CH 64        // producer i-chunks (18 i each), 4 b per wave

__device__ __forceinline__ float dot8(const float4 w0, const float4 w1,
                                      const float4 ua, const float4 ub) {
    return w0.x*ua.x + w0.y*ua.y + w0.z*ua.z + w0.w*ua.w
         + w1.x*ub.x + w1.y*ub.y + w1.z*ub.z + w1.w*ub.w;
}

__device__ __forceinline__ unsigned short bf16_rn(float x) {
    unsigned u = __float_as_uint(x);
    u += 0x7FFFu + ((u >> 16) & 1u);
    return (unsigned short)(u >> 16);
}
__device__ __forceinline__ float bf16_to_f(unsigned short h) {
    return __uint_as_float(((unsigned)h) << 16);
}

// quad-local squash: lane q holds 4 of the 16 dims of class c=q>>2; the
// 4 lanes of the quad group hold all 16. ns via shfl_xor{1,2}.
__device__ __forceinline__ float4 squash4(float4 x) {
    float ns = x.x*x.x + x.y*x.y + x.z*x.z + x.w*x.w;
    ns += __shfl_xor(ns, 1);
    ns += __shfl_xor(ns, 2);
    const float sc = ns * __builtin_amdgcn_rcpf((1.0f + ns) * (sqrtf(ns) + 1e-8f));
    return make_float4(x.x*sc, x.y*sc, x.z*sc, x.w*sc);
}

// ---------------- W transpose: W[i][c][d][k] -> W_t[i][j][q] (float4 units) ----------------
__global__ void transpose_W(const float4* __restrict__ W4, float4* __restrict__ Wt4)
{
    int tid = blockIdx.x * 256 + threadIdx.x;
    if (tid >= 1152 * 320) return;
    int i = tid / 320, r = tid - i * 320;
    int q = r >> 3, j = r & 7;
    Wt4[i * 320 + j * 40 + q] = W4[tid];   // read coalesced, scatter within 5 KB row
}

// ---------------- Producer (R15 VERBATIM): u_hat bf16 + fused pass-0 sum, LDS reduce ----------------
// K1_CH 64 -> 18 i/wave, 8192 waves, grid 2048 = 8 blocks/CU (VGPR 64 tier),
// one uniform round. Block's 4 waves share the b-quad: waves 1-3 park acc in
// LDS, wave 0 alone issues atomics. DO NOT add prefetch/double-buffer.
__global__ __launch_bounds__(256, 4)
void produce_uhat_t(const float* __restrict__ u, const float* __restrict__ Wt,
                    unsigned short* __restrict__ uhat_h, float* __restrict__ s0)
{
    const int t = threadIdx.x, lane = t & 63, wv = t >> 6;
    const int gid = blockIdx.x * 4 + wv;
    const int bq  = gid / K1_CH;          // 0..127 (same for all 4 waves of a block)
    const int ch  = gid - bq * K1_CH;     // 0..63
    const int b0  = bq * 4;
    const int i0  = ch * 18;
    const int q   = lane;
    const bool act = (q < UHQ);

    __shared__ float4 red[480];           // 3 waves x 40 lanes x 4 float4 = 7680 B

    float4 acc[4];
    #pragma unroll
    for (int bb = 0; bb < 4; ++bb) acc[bb] = make_float4(0.f, 0.f, 0.f, 0.f);

    for (int ii = 0; ii < 18; ++ii) {
        const int i = i0 + ii;
        float4 w4[8];
        if (act) {
            const float4* wb = (const float4*)(Wt + (size_t)i * 1280);
            #pragma unroll
            for (int j = 0; j < 8; ++j) w4[j] = wb[j * 40 + q];   // 640 B contiguous
        }
        #pragma unroll
        for (int bb = 0; bb < 4; ++bb) {
            const int b = b0 + bb;
            const float4* up = (const float4*)(u + ((size_t)b * 1152 + i) * 8);
            const float4 ua = up[0], ub = up[1];   // wave-uniform broadcast
            if (act) {
                float4 uh;
                uh.x = dot8(w4[0], w4[1], ua, ub);
                uh.y = dot8(w4[2], w4[3], ua, ub);
                uh.z = dot8(w4[4], w4[5], ua, ub);
                uh.w = dot8(w4[6], w4[7], ua, ub);
                acc[bb].x += uh.x; acc[bb].y += uh.y;
                acc[bb].z += uh.z; acc[bb].w += uh.w;
                ushort4 h;
                h.x = bf16_rn(uh.x); h.y = bf16_rn(uh.y);
                h.z = bf16_rn(uh.z); h.w = bf16_rn(uh.w);
                ((ushort4*)uhat_h)[((size_t)b * 1152 + i) * UHQ + q] = h;
            }
        }
    }

    // cross-wave reduction of the pass-0 partial sums
    if (wv > 0 && act) {
        float4* rp = red + ((wv - 1) * 40 + q) * 4;
        rp[0] = acc[0]; rp[1] = acc[1]; rp[2] = acc[2]; rp[3] = acc[3];
    }
    __syncthreads();
    if (wv == 0 && act) {
        #pragma unroll
        for (int w = 0; w < 3; ++w) {
            const float4* rp = red + (w * 40 + q) * 4;
            #pragma unroll
            for (int bb = 0; bb < 4; ++bb) {
                const float4 r = rp[bb];
                acc[bb].x += r.x; acc[bb].y += r.y;
                acc[bb].z += r.z; acc[bb].w += r.w;
            }
        }
#if defined(__HIP_DEVICE_COMPILE__)
        #pragma unroll
        for (int bb = 0; bb < 4; ++bb) {
            float* sp = s0 + (size_t)(b0 + bb) * 160 + q * 4;
            unsafeAtomicAdd(sp + 0, acc[bb].x);
            unsafeAtomicAdd(sp + 1, acc[bb].y);
            unsafeAtomicAdd(sp + 2, acc[bb].z);
            unsafeAtomicAdd(sp + 3, acc[bb].w);
        }
#endif
    }
}

// ---------------- Producer fallback (divergent W, no W_t buffer; R9 geometry) ----------------
__global__ __launch_bounds__(256, 4)
void produce_uhat_div(const float* __restrict__ u, const float* __restrict__ W,
                      unsigned short* __restrict__ uhat_h, float* __restrict__ s0)
{
    const int t = threadIdx.x, lane = t & 63, wv = t >> 6;
    const int gid = blockIdx.x * 4 + wv;
    const int bq  = gid / 32;
    const int ch  = gid - bq * 32;
    const int b0  = bq * 4;
    const int i0  = ch * 36;
    const int q   = lane;
    const bool act = (q < UHQ);

    float4 acc[4];
    #pragma unroll
    for (int bb = 0; bb < 4; ++bb) acc[bb] = make_float4(0.f, 0.f, 0.f, 0.f);

    for (int ii = 0; ii < 36; ++ii) {
        const int i = i0 + ii;
        float4 w4[8];
        if (act) {
            const float4* wp = (const float4*)(W + (size_t)i * 1280 + q * 32);
            #pragma unroll
            for (int j = 0; j < 8; ++j) w4[j] = wp[j];
        }
        #pragma unroll
        for (int bb = 0; bb < 4; ++bb) {
            const int b = b0 + bb;
            const float4* up = (const float4*)(u + ((size_t)b * 1152 + i) * 8);
            const float4 ua = up[0], ub = up[1];
            if (act) {
                float4 uh;
                uh.x = dot8(w4[0], w4[1], ua, ub);
                uh.y = dot8(w4[2], w4[3], ua, ub);
                uh.z = dot8(w4[4], w4[5], ua, ub);
                uh.w = dot8(w4[6], w4[7], ua, ub);
                acc[bb].x += uh.x; acc[bb].y += uh.y;
                acc[bb].z += uh.z; acc[bb].w += uh.w;
                ushort4 h;
                h.x = bf16_rn(uh.x); h.y = bf16_rn(uh.y);
                h.z = bf16_rn(uh.z); h.w = bf16_rn(uh.w);
                ((ushort4*)uhat_h)[((size_t)b * 1152 + i) * UHQ + q] = h;
            }
        }
    }
    if (act) {
#if defined(__HIP_DEVICE_COMPILE__)
        #pragma unroll
        for (int bb = 0; bb < 4; ++bb) {
            float* sp = s0 + (size_t)(b0 + bb) * 160 + q * 4;
            unsafeAtomicAdd(sp + 0, acc[bb].x);
            unsafeAtomicAdd(sp + 1, acc[bb].y);
            unsafeAtomicAdd(sp + 2, acc[bb].z);
            unsafeAtomicAdd(sp + 3, acc[bb].w);
        }
#endif
    }
}

// ---------------- Routing pass v6s: cd-quad route + INLINE squash prologue ----------------
// Wave owns (b, i-chunk); lane q = cd-quad (40/64 active). VGPR ~25 ->
// 8 waves/SIMD; grid 2048 = 8 blocks/CU, one uniform round. The v-vector is
// computed inline from the raw s accumulators (quad-local squash) instead of
// a separate squash kernel: PASS1 va=squash(s0*0.1); PASS2 += squash(s1).
template <int PASS>
__global__ __launch_bounds__(256, 8)
void route6s(const unsigned short* __restrict__ uhat_h,
             const float* __restrict__ s0g, const float* __restrict__ s1g,
             float* __restrict__ sg)
{
    const int t = threadIdx.x, lane = t & 63, wv = t >> 6;
    const int gid = blockIdx.x * 4 + wv;
    const int b   = gid >> 4;             // 0..511
    const int ch  = gid & 15;             // 0..15
    const int i0  = ch * 72;
    const int q   = lane;
    const bool act = (q < UHQ);

    // inline squash prologue (once per wave; all lanes run the shfls)
    float4 va;
    {
        float4 x0 = make_float4(0.f, 0.f, 0.f, 0.f);
        if (act) x0 = ((const float4*)s0g)[(size_t)b * UHQ + q];
        x0.x *= 0.1f; x0.y *= 0.1f; x0.z *= 0.1f; x0.w *= 0.1f;
        va = squash4(x0);
        if (PASS == 2) {
            float4 x1 = make_float4(0.f, 0.f, 0.f, 0.f);
            if (act) x1 = ((const float4*)s1g)[(size_t)b * UHQ + q];
            const float4 v1 = squash4(x1);
            va.x += v1.x; va.y += v1.y; va.z += v1.z; va.w += v1.w;
        }
    }
    float4 sacc = make_float4(0.f, 0.f, 0.f, 0.f);

    const ushort4* up = (const ushort4*)uhat_h;

    for (int ii = 0; ii < 72; ii += 2) {
        const size_t qi = ((size_t)b * 1152 + i0 + ii) * UHQ + q;
        float4 uh0 = make_float4(0.f, 0.f, 0.f, 0.f);
        float4 uh1 = make_float4(0.f, 0.f, 0.f, 0.f);
        if (act) {
            const ushort4 h0 = up[qi];
            const ushort4 h1 = up[qi + UHQ];
            uh0.x = bf16_to_f(h0.x); uh0.y = bf16_to_f(h0.y);
            uh0.z = bf16_to_f(h0.z); uh0.w = bf16_to_f(h0.w);
            uh1.x = bf16_to_f(h1.x); uh1.y = bf16_to_f(h1.y);
            uh1.z = bf16_to_f(h1.z); uh1.w = bf16_to_f(h1.w);
        }
        // per-c logit: 4-lane segmented reduction (two independent chains)
        float p0 = uh0.x*va.x + uh0.y*va.y + uh0.z*va.z + uh0.w*va.w;
        float p1 = uh1.x*va.x + uh1.y*va.y + uh1.z*va.z + uh1.w*va.w;
        p0 += __shfl_xor(p0, 1);  p1 += __shfl_xor(p1, 1);
        p0 += __shfl_xor(p0, 2);  p1 += __shfl_xor(p1, 2);
        // softmax, no max-subtraction (|logit| < ~0.5); mask inactive lanes
        const float e0 = act ? __expf(p0) : 0.0f;
        const float e1 = act ? __expf(p1) : 0.0f;
        float s0v = e0, s1v = e1;
        // xor-butterfly over strides 4..32: every lane gets sum over the 10 c-groups
        s0v += __shfl_xor(s0v, 4);   s1v += __shfl_xor(s1v, 4);
        s0v += __shfl_xor(s0v, 8);   s1v += __shfl_xor(s1v, 8);
        s0v += __shfl_xor(s0v, 16);  s1v += __shfl_xor(s1v, 16);
        s0v += __shfl_xor(s0v, 32);  s1v += __shfl_xor(s1v, 32);
        const float c0 = e0 * __builtin_amdgcn_rcpf(s0v);
        const float c1 = e1 * __builtin_amdgcn_rcpf(s1v);
        sacc.x += c0 * uh0.x + c1 * uh1.x;
        sacc.y += c0 * uh0.y + c1 * uh1.y;
        sacc.z += c0 * uh0.z + c1 * uh1.z;
        sacc.w += c0 * uh0.w + c1 * uh1.w;
    }
    if (act) {
#if defined(__HIP_DEVICE_COMPILE__)
        float* sp = sg + (size_t)b * 160 + q * 4;
        unsafeAtomicAdd(sp + 0, sacc.x);
        unsafeAtomicAdd(sp + 1, sacc.y);
        unsafeAtomicAdd(sp + 2, sacc.z);
        unsafeAtomicAdd(sp + 3, sacc.w);
#endif
    }
}

// ---------------- squash with pre-scale (final output only) ----------------
__global__ void squash_scale(const float* __restrict__ s, float* __restrict__ vout,
                             float scale)
{
    int r = blockIdx.x * 256 + threadIdx.x;
    if (r >= 512 * 10) return;
    const float* sp = s + (size_t)r * 16;
    float sv[16];
    float ns = 0.0f;
    #pragma unroll
    for (int d = 0; d < 16; ++d) {
        float x = sp[d] * scale;
        sv[d] = x;
        ns += x * x;
    }
    float sc = ns / ((1.0f + ns) * (sqrtf(ns) + 1e-8f));
    float* o = vout + (size_t)r * 16;
    #pragma unroll
    for (int d = 0; d < 16; ++d) o[d] = sv[d] * sc;
}

// ---------------- tiny-ws fallback (R3-style): thread owns (b,c) ----------------
template <int PASS>
__global__ __launch_bounds__(256, 4)
void pass_fb(const float* __restrict__ u, const float* __restrict__ W,
             const float* __restrict__ v0g, const float* __restrict__ v1g,
             float* __restrict__ s_atomic)
{
    const int t    = threadIdx.x;
    const int lane = t & 63;
    const int wv   = t >> 6;
    const int bsub = lane / 10;
    const int c    = lane - bsub * 10;
    const bool lane_ok = (bsub < 6);
    const int b    = blockIdx.y * 24 + wv * 6 + bsub;
    const bool valid = lane_ok && (b < 512);
    const int bc   = valid ? b : 511;
    const int base = lane_ok ? bsub * 10 : 0;
    const int i0   = blockIdx.x * 24;

    float v[16];
    #pragma unroll
    for (int d = 0; d < 16; ++d) v[d] = 0.0f;
    if (PASS >= 1) {
        const float* vp = v0g + ((size_t)bc * 10 + c) * 16;
        #pragma unroll
        for (int d = 0; d < 16; ++d) v[d] = vp[d];
        if (PASS >= 2) {
            const float* vq = v1g + ((size_t)bc * 10 + c) * 16;
            #pragma unroll
            for (int d = 0; d < 16; ++d) v[d] += vq[d];
        }
    }

    float s_acc[16];
    #pragma unroll
    for (int d = 0; d < 16; ++d) s_acc[d] = 0.0f;

    for (int ii = 0; ii < 24; ++ii) {
        const int i = i0 + ii;
        const float4* up = (const float4*)(u + ((size_t)bc * 1152 + i) * 8);
        const float4 ua = up[0];
        const float4 ub = up[1];
        const float* Wp = W + ((size_t)i * 10 + c) * 128;

        float h[16];
        #pragma unroll
        for (int d = 0; d < 16; ++d) {
            const float4* wp = (const float4*)(Wp + d * 8);
            h[d] = dot8(wp[0], wp[1], ua, ub);
        }

        if (PASS == 0) {
            #pragma unroll
            for (int d = 0; d < 16; ++d) s_acc[d] += h[d];
        } else {
            float lg = 0.0f;
            #pragma unroll
            for (int d = 0; d < 16; ++d) lg += h[d] * v[d];
            float lj[10];
            #pragma unroll
            for (int j = 0; j < 10; ++j) lj[j] = __shfl(lg, base + j);
            float m = lj[0];
            #pragma unroll
            for (int j = 1; j < 10; ++j) m = fmaxf(m, lj[j]);
            float sum = 0.0f;
            #pragma unroll
            for (int j = 0; j < 10; ++j) sum += __expf(lj[j] - m);
            const float coef = __expf(lg - m) / sum;
            #pragma unroll
            for (int d = 0; d < 16; ++d) s_acc[d] += coef * h[d];
        }
    }
    if (PASS == 0) {
        #pragma unroll
        for (int d = 0; d < 16; ++d) s_acc[d] *= 0.1f;
    }
    if (valid) {
#if defined(__HIP_DEVICE_COMPILE__)
        #pragma unroll
        for (int d = 0; d < 16; ++d)
            unsafeAtomicAdd(&s_atomic[((size_t)b * 10 + c) * 16 + d], s_acc[d]);
#endif
    }
}

extern "C" void kernel_launch(void* const* d_in, const int* in_sizes, int n_in,
                              void* d_out, int out_size, void* d_ws, size_t ws_size,
                              hipStream_t stream)
{
    const float* u = (const float*)d_in[0];   // [512,1152,8]
    const float* W = (const float*)d_in[1];   // [1152,10,16,8]
    float* out = (float*)d_out;               // [512,10,16]

    float* v0 = (float*)d_ws;
    float* v1 = v0 + 81920;
    float* s0 = v1 + 81920;
    float* s1 = s0 + 81920;
    float* s2 = s1 + 81920;
    float* wt = s2 + 81920;                   // 1,474,560 f32 (5.9 MB)

    const size_t head   = (size_t)5 * 81920 * sizeof(float);          // 1.64 MB
    const size_t wtsz   = (size_t)1152 * 1280 * sizeof(float);        // 5.90 MB
    const size_t uh_b16 = (size_t)512 * 1152 * 160 * 2;               // 188.7 MB

    hipMemsetAsync(s0, 0, (size_t)3 * 81920 * sizeof(float), stream);

    dim3 blk(256);

    if (ws_size >= head + wtsz + uh_b16) {
        unsigned short* uhh = (unsigned short*)(wt + 1152 * 1280);
        transpose_W<<<1440, blk, 0, stream>>>((const float4*)W, (float4*)wt);
        produce_uhat_t<<<2048, blk, 0, stream>>>(u, wt, uhh, s0);
        route6s<1><<<2048, blk, 0, stream>>>(uhh, s0, nullptr, s1);
        route6s<2><<<2048, blk, 0, stream>>>(uhh, s0, s1, s2);
        squash_scale<<<20, blk, 0, stream>>>(s2, out, 1.0f);
    } else if (ws_size >= head + uh_b16) {
        unsigned short* uhh = (unsigned short*)wt;   // no W_t buffer
        produce_uhat_div<<<1024, blk, 0, stream>>>(u, W, uhh, s0);
        route6s<1><<<2048, blk, 0, stream>>>(uhh, s0, nullptr, s1);
        route6s<2><<<2048, blk, 0, stream>>>(uhh, s0, s1, s2);
        squash_scale<<<20, blk, 0, stream>>>(s2, out, 1.0f);
    } else {
        dim3 grid(48, 22);
        pass_fb<0><<<grid, blk, 0, stream>>>(u, W, nullptr, nullptr, s0);
        squash_scale<<<20, blk, 0, stream>>>(s0, v0, 1.0f);
        pass_fb<1><<<grid, blk, 0, stream>>>(u, W, v0, nullptr, s1);
        squash_scale<<<20, blk, 0, stream>>>(s1, v1, 1.0f);
        pass_fb<2><<<grid, blk, 0, stream>>>(u, W, v0, v1, s2);
        squash_scale<<<20, blk, 0, stream>>>(s2, out, 1.0f);
    }
}

// Round 15
// 250.539 us; speedup vs baseline: 1.3442x; 1.1798x over previous
//
#include <hip/hip_runtime.h>
#include <math.h>

// DigitCaps dynamic routing. B=512, I=1152, K=8, C=10, D=16, 3 iters.
//
// Best-known = R18 (291.0 / 295.6 us, noise ~1.5%). Session ledger:
// R5 structure: materialize bf16 u_hat (189 MB) in ws; each routing pass
//   streams it once; softmax fully in-register.
// Producer dead-ends (5/5): ILP prefetch folded (R11); forced launch_bounds
//   spills (R7); b-oct spills + red[] conflicts (R16); sched_barrier pins
//   spilling loads (R17, FETCH 16->177 MB); b-pairs double W_t loads (R12).
// Route dead-ends (4/4 since route6): c-lane >=80 VGPR loses 8-wave tier
//   (R13); 4-wide = no gain (R16); global_load_lds staging loses L3
//   residency + vmcnt(0) drain serializes (R19).
// Structural wins: R14 route TLP (cd-quad VGPR~20, grid 2048); R15 LDS
//   cross-wave reduce (atomics /4); R18 squash fused into route prologue.
// R21 (this round): producer cycle model says ~30us at any roofline vs 128
//   measured -> unhidden VMEM latency. Last untested mechanism: the per-ii
//   u loads (8 VMEM/ii if not scalarized). Stage the block's u slab (4 b x
//   72 i = 9.2 KB) in LDS once; inner loop reads u via broadcast ds_read.
//   Zero extra live VGPR (no spill risk). Memset folded into transpose_W.
//   Falsifier: neutral dur => u was scalarized; R18 is the final answer.

#define UHQ 40          // ushort4 quads per (b,i) row (160 bf16 elems)
#define K1_CH 64        // producer i-chunks (18 i each), 4 b per wave

__device__ __forceinline__ float dot8(const float4 w0, const float4 w1,
                                      const float4 ua, const float4 ub) {
    return w0.x*ua.x + w0.y*ua.y + w0.z*ua.z + w0.w*ua.w
         + w1.x*ub.x + w1.y*ub.y + w1.z*ub.z + w1.w*ub.w;
}

__device__ __forceinline__ unsigned short bf16_rn(float x) {
    unsigned u = __float_as_uint(x);
    u += 0x7FFFu + ((u >> 16) & 1u);
    return (unsigned short)(u >> 16);
}
__device__ __forceinline__ float bf16_to_f(unsigned short h) {
    return __uint_as_float(((unsigned)h) << 16);
}

// quad-local squash: lane q holds 4 of the 16 dims of class c=q>>2; the
// 4 lanes of the quad group hold all 16. ns via shfl_xor{1,2}.
__device__ __forceinline__ float4 squash4(float4 x) {
    float ns = x.x*x.x + x.y*x.y + x.z*x.z + x.w*x.w;
    ns += __shfl_xor(ns, 1);
    ns += __shfl_xor(ns, 2);
    const float sc = ns * __builtin_amdgcn_rcpf((1.0f + ns) * (sqrtf(ns) + 1e-8f));
    return make_float4(x.x*sc, x.y*sc, x.z*sc, x.w*sc);
}

// ---------------- W transpose + s-buffer zeroing ----------------
// W[i][c][d][k] -> W_t[i][j][q] (float4 units); also zeroes s0..s2
// (61440 float4) to drop the separate memset dispatch.
__global__ void transpose_W(const float4* __restrict__ W4, float4* __restrict__ Wt4,
                            float4* __restrict__ zbuf)
{
    int tid = blockIdx.x * 256 + threadIdx.x;
    if (tid < 61440) zbuf[tid] = make_float4(0.f, 0.f, 0.f, 0.f);
    if (tid >= 1152 * 320) return;
    int i = tid / 320, r = tid - i * 320;
    int q = r >> 3, j = r & 7;
    Wt4[i * 320 + j * 40 + q] = W4[tid];   // read coalesced, scatter within 5 KB row
}

// ---------------- Producer: u staged in LDS + fused pass-0 sum, LDS reduce ----------------
// K1_CH 64 -> 18 i/wave, 8192 waves, grid 2048 = 8 blocks/CU (VGPR 64 tier).
// Block's 4 waves share the b-quad AND a contiguous 72-i slab: u (9.2 KB)
// cooperatively staged in LDS once, inner loop reads it via broadcast
// ds_read (removes 8 VMEM ops per ii; zero extra live VGPR). Waves 1-3 park
// pass-0 acc in LDS, wave 0 alone issues atomics. DO NOT add W_t prefetch
// (R11/R16/R17: folds or spills).
__global__ __launch_bounds__(256, 4)
void produce_uhat_t(const float* __restrict__ u, const float* __restrict__ Wt,
                    unsigned short* __restrict__ uhat_h, float* __restrict__ s0)
{
    const int t = threadIdx.x, lane = t & 63, wv = t >> 6;
    const int gid = blockIdx.x * 4 + wv;
    const int bq  = gid / K1_CH;          // 0..127 (same for all 4 waves of a block)
    const int ch  = gid - bq * K1_CH;     // 0..63
    const int b0  = bq * 4;
    const int q   = lane;
    const bool act = (q < UHQ);

    __shared__ float4 red[480];           // 3 waves x 40 lanes x 4 float4 = 7680 B
    __shared__ float4 uL[576];            // u[b0..b0+4)[iblk0..iblk0+72)[8f] = 9216 B

    const int iblk0 = ((blockIdx.x & 15) * 4) * 18;   // block's i-slab start

    // cooperative stage of the block's u slab (576 float4, 256 threads)
    {
        const float4* u4 = (const float4*)u;          // [512][1152][2] float4
        #pragma unroll
        for (int idx = t; idx < 576; idx += 256) {
            const int bb = idx / 144;                 // 0..3
            const int r  = idx - bb * 144;            // 0..143
            uL[idx] = u4[((size_t)(b0 + bb) * 1152 + iblk0) * 2 + r];
        }
    }
    __syncthreads();

    float4 acc[4];
    #pragma unroll
    for (int bb = 0; bb < 4; ++bb) acc[bb] = make_float4(0.f, 0.f, 0.f, 0.f);

    for (int ii = 0; ii < 18; ++ii) {
        const int il = wv * 18 + ii;      // i - iblk0, 0..71
        const int i  = iblk0 + il;
        float4 w4[8];
        if (act) {
            const float4* wb = (const float4*)(Wt + (size_t)i * 1280);
            #pragma unroll
            for (int j = 0; j < 8; ++j) w4[j] = wb[j * 40 + q];   // 640 B contiguous
        }
        #pragma unroll
        for (int bb = 0; bb < 4; ++bb) {
            const int b = b0 + bb;
            const float4* us = &uL[(bb * 72 + il) * 2];
            const float4 ua = us[0], ub = us[1];   // broadcast ds_read, conflict-free
            if (act) {
                float4 uh;
                uh.x = dot8(w4[0], w4[1], ua, ub);
                uh.y = dot8(w4[2], w4[3], ua, ub);
                uh.z = dot8(w4[4], w4[5], ua, ub);
                uh.w = dot8(w4[6], w4[7], ua, ub);
                acc[bb].x += uh.x; acc[bb].y += uh.y;
                acc[bb].z += uh.z; acc[bb].w += uh.w;
                ushort4 h;
                h.x = bf16_rn(uh.x); h.y = bf16_rn(uh.y);
                h.z = bf16_rn(uh.z); h.w = bf16_rn(uh.w);
                ((ushort4*)uhat_h)[((size_t)b * 1152 + i) * UHQ + q] = h;
            }
        }
    }

    // cross-wave reduction of the pass-0 partial sums
    if (wv > 0 && act) {
        float4* rp = red + ((wv - 1) * 40 + q) * 4;
        rp[0] = acc[0]; rp[1] = acc[1]; rp[2] = acc[2]; rp[3] = acc[3];
    }
    __syncthreads();
    if (wv == 0 && act) {
        #pragma unroll
        for (int w = 0; w < 3; ++w) {
            const float4* rp = red + (w * 40 + q) * 4;
            #pragma unroll
            for (int bb = 0; bb < 4; ++bb) {
                const float4 r = rp[bb];
                acc[bb].x += r.x; acc[bb].y += r.y;
                acc[bb].z += r.z; acc[bb].w += r.w;
            }
        }
#if defined(__HIP_DEVICE_COMPILE__)
        #pragma unroll
        for (int bb = 0; bb < 4; ++bb) {
            float* sp = s0 + (size_t)(b0 + bb) * 160 + q * 4;
            unsafeAtomicAdd(sp + 0, acc[bb].x);
            unsafeAtomicAdd(sp + 1, acc[bb].y);
            unsafeAtomicAdd(sp + 2, acc[bb].z);
            unsafeAtomicAdd(sp + 3, acc[bb].w);
        }
#endif
    }
}

// ---------------- Producer fallback (divergent W, no W_t buffer; R9 geometry) ----------------
__global__ __launch_bounds__(256, 4)
void produce_uhat_div(const float* __restrict__ u, const float* __restrict__ W,
                      unsigned short* __restrict__ uhat_h, float* __restrict__ s0)
{
    const int t = threadIdx.x, lane = t & 63, wv = t >> 6;
    const int gid = blockIdx.x * 4 + wv;
    const int bq  = gid / 32;
    const int ch  = gid - bq * 32;
    const int b0  = bq * 4;
    const int i0  = ch * 36;
    const int q   = lane;
    const bool act = (q < UHQ);

    float4 acc[4];
    #pragma unroll
    for (int bb = 0; bb < 4; ++bb) acc[bb] = make_float4(0.f, 0.f, 0.f, 0.f);

    for (int ii = 0; ii < 36; ++ii) {
        const int i = i0 + ii;
        float4 w4[8];
        if (act) {
            const float4* wp = (const float4*)(W + (size_t)i * 1280 + q * 32);
            #pragma unroll
            for (int j = 0; j < 8; ++j) w4[j] = wp[j];
        }
        #pragma unroll
        for (int bb = 0; bb < 4; ++bb) {
            const int b = b0 + bb;
            const float4* up = (const float4*)(u + ((size_t)b * 1152 + i) * 8);
            const float4 ua = up[0], ub = up[1];
            if (act) {
                float4 uh;
                uh.x = dot8(w4[0], w4[1], ua, ub);
                uh.y = dot8(w4[2], w4[3], ua, ub);
                uh.z = dot8(w4[4], w4[5], ua, ub);
                uh.w = dot8(w4[6], w4[7], ua, ub);
                acc[bb].x += uh.x; acc[bb].y += uh.y;
                acc[bb].z += uh.z; acc[bb].w += uh.w;
                ushort4 h;
                h.x = bf16_rn(uh.x); h.y = bf16_rn(uh.y);
                h.z = bf16_rn(uh.z); h.w = bf16_rn(uh.w);
                ((ushort4*)uhat_h)[((size_t)b * 1152 + i) * UHQ + q] = h;
            }
        }
    }
    if (act) {
#if defined(__HIP_DEVICE_COMPILE__)
        #pragma unroll
        for (int bb = 0; bb < 4; ++bb) {
            float* sp = s0 + (size_t)(b0 + bb) * 160 + q * 4;
            unsafeAtomicAdd(sp + 0, acc[bb].x);
            unsafeAtomicAdd(sp + 1, acc[bb].y);
            unsafeAtomicAdd(sp + 2, acc[bb].z);
            unsafeAtomicAdd(sp + 3, acc[bb].w);
        }
#endif
    }
}

// ---------------- Routing pass v6s (R18 WIN config, FROZEN) ----------------
// Wave owns (b, i-chunk); lane q = cd-quad (40/64 active). VGPR ~25 ->
// 8 waves/SIMD; grid 2048 = 8 blocks/CU, one uniform round. v computed
// inline from raw s accumulators (quad-local squash).
template <int PASS>
__global__ __launch_bounds__(256, 8)
void route6s(const unsigned short* __restrict__ uhat_h,
             const float* __restrict__ s0g, const float* __restrict__ s1g,
             float* __restrict__ sg)
{
    const int t = threadIdx.x, lane = t & 63, wv = t >> 6;
    const int gid = blockIdx.x * 4 + wv;
    const int b   = gid >> 4;             // 0..511
    const int ch  = gid & 15;             // 0..15
    const int i0  = ch * 72;
    const int q   = lane;
    const bool act = (q < UHQ);

    // inline squash prologue (once per wave; all lanes run the shfls)
    float4 va;
    {
        float4 x0 = make_float4(0.f, 0.f, 0.f, 0.f);
        if (act) x0 = ((const float4*)s0g)[(size_t)b * UHQ + q];
        x0.x *= 0.1f; x0.y *= 0.1f; x0.z *= 0.1f; x0.w *= 0.1f;
        va = squash4(x0);
        if (PASS == 2) {
            float4 x1 = make_float4(0.f, 0.f, 0.f, 0.f);
            if (act) x1 = ((const float4*)s1g)[(size_t)b * UHQ + q];
            const float4 v1 = squash4(x1);
            va.x += v1.x; va.y += v1.y; va.z += v1.z; va.w += v1.w;
        }
    }
    float4 sacc = make_float4(0.f, 0.f, 0.f, 0.f);

    const ushort4* up = (const ushort4*)uhat_h;

    for (int ii = 0; ii < 72; ii += 2) {
        const size_t qi = ((size_t)b * 1152 + i0 + ii) * UHQ + q;
        float4 uh0 = make_float4(0.f, 0.f, 0.f, 0.f);
        float4 uh1 = make_float4(0.f, 0.f, 0.f, 0.f);
        if (act) {
            const ushort4 h0 = up[qi];
            const ushort4 h1 = up[qi + UHQ];
            uh0.x = bf16_to_f(h0.x); uh0.y = bf16_to_f(h0.y);
            uh0.z = bf16_to_f(h0.z); uh0.w = bf16_to_f(h0.w);
            uh1.x = bf16_to_f(h1.x); uh1.y = bf16_to_f(h1.y);
            uh1.z = bf16_to_f(h1.z); uh1.w = bf16_to_f(h1.w);
        }
        // per-c logit: 4-lane segmented reduction (two independent chains)
        float p0 = uh0.x*va.x + uh0.y*va.y + uh0.z*va.z + uh0.w*va.w;
        float p1 = uh1.x*va.x + uh1.y*va.y + uh1.z*va.z + uh1.w*va.w;
        p0 += __shfl_xor(p0, 1);  p1 += __shfl_xor(p1, 1);
        p0 += __shfl_xor(p0, 2);  p1 += __shfl_xor(p1, 2);
        // softmax, no max-subtraction (|logit| < ~0.5); mask inactive lanes
        const float e0 = act ? __expf(p0) : 0.0f;
        const float e1 = act ? __expf(p1) : 0.0f;
        float s0v = e0, s1v = e1;
        // xor-butterfly over strides 4..32: every lane gets sum over the 10 c-groups
        s0v += __shfl_xor(s0v, 4);   s1v += __shfl_xor(s1v, 4);
        s0v += __shfl_xor(s0v, 8);   s1v += __shfl_xor(s1v, 8);
        s0v += __shfl_xor(s0v, 16);  s1v += __shfl_xor(s1v, 16);
        s0v += __shfl_xor(s0v, 32);  s1v += __shfl_xor(s1v, 32);
        const float c0 = e0 * __builtin_amdgcn_rcpf(s0v);
        const float c1 = e1 * __builtin_amdgcn_rcpf(s1v);
        sacc.x += c0 * uh0.x + c1 * uh1.x;
        sacc.y += c0 * uh0.y + c1 * uh1.y;
        sacc.z += c0 * uh0.z + c1 * uh1.z;
        sacc.w += c0 * uh0.w + c1 * uh1.w;
    }
    if (act) {
#if defined(__HIP_DEVICE_COMPILE__)
        float* sp = sg + (size_t)b * 160 + q * 4;
        unsafeAtomicAdd(sp + 0, sacc.x);
        unsafeAtomicAdd(sp + 1, sacc.y);
        unsafeAtomicAdd(sp + 2, sacc.z);
        unsafeAtomicAdd(sp + 3, sacc.w);
#endif
    }
}

// ---------------- squash with pre-scale (final output only) ----------------
__global__ void squash_scale(const float* __restrict__ s, float* __restrict__ vout,
                             float scale)
{
    int r = blockIdx.x * 256 + threadIdx.x;
    if (r >= 512 * 10) return;
    const float* sp = s + (size_t)r * 16;
    float sv[16];
    float ns = 0.0f;
    #pragma unroll
    for (int d = 0; d < 16; ++d) {
        float x = sp[d] * scale;
        sv[d] = x;
        ns += x * x;
    }
    float sc = ns / ((1.0f + ns) * (sqrtf(ns) + 1e-8f));
    float* o = vout + (size_t)r * 16;
    #pragma unroll
    for (int d = 0; d < 16; ++d) o[d] = sv[d] * sc;
}

// ---------------- tiny-ws fallback (R3-style): thread owns (b,c) ----------------
template <int PASS>
__global__ __launch_bounds__(256, 4)
void pass_fb(const float* __restrict__ u, const float* __restrict__ W,
             const float* __restrict__ v0g, const float* __restrict__ v1g,
             float* __restrict__ s_atomic)
{
    const int t    = threadIdx.x;
    const int lane = t & 63;
    const int wv   = t >> 6;
    const int bsub = lane / 10;
    const int c    = lane - bsub * 10;
    const bool lane_ok = (bsub < 6);
    const int b    = blockIdx.y * 24 + wv * 6 + bsub;
    const bool valid = lane_ok && (b < 512);
    const int bc   = valid ? b : 511;
    const int base = lane_ok ? bsub * 10 : 0;
    const int i0   = blockIdx.x * 24;

    float v[16];
    #pragma unroll
    for (int d = 0; d < 16; ++d) v[d] = 0.0f;
    if (PASS >= 1) {
        const float* vp = v0g + ((size_t)bc * 10 + c) * 16;
        #pragma unroll
        for (int d = 0; d < 16; ++d) v[d] = vp[d];
        if (PASS >= 2) {
            const float* vq = v1g + ((size_t)bc * 10 + c) * 16;
            #pragma unroll
            for (int d = 0; d < 16; ++d) v[d] += vq[d];
        }
    }

    float s_acc[16];
    #pragma unroll
    for (int d = 0; d < 16; ++d) s_acc[d] = 0.0f;

    for (int ii = 0; ii < 24; ++ii) {
        const int i = i0 + ii;
        const float4* up = (const float4*)(u + ((size_t)bc * 1152 + i) * 8);
        const float4 ua = up[0];
        const float4 ub = up[1];
        const float* Wp = W + ((size_t)i * 10 + c) * 128;

        float h[16];
        #pragma unroll
        for (int d = 0; d < 16; ++d) {
            const float4* wp = (const float4*)(Wp + d * 8);
            h[d] = dot8(wp[0], wp[1], ua, ub);
        }

        if (PASS == 0) {
            #pragma unroll
            for (int d = 0; d < 16; ++d) s_acc[d] += h[d];
        } else {
            float lg = 0.0f;
            #pragma unroll
            for (int d = 0; d < 16; ++d) lg += h[d] * v[d];
            float lj[10];
            #pragma unroll
            for (int j = 0; j < 10; ++j) lj[j] = __shfl(lg, base + j);
            float m = lj[0];
            #pragma unroll
            for (int j = 1; j < 10; ++j) m = fmaxf(m, lj[j]);
            float sum = 0.0f;
            #pragma unroll
            for (int j = 0; j < 10; ++j) sum += __expf(lj[j] - m);
            const float coef = __expf(lg - m) / sum;
            #pragma unroll
            for (int d = 0; d < 16; ++d) s_acc[d] += coef * h[d];
        }
    }
    if (PASS == 0) {
        #pragma unroll
        for (int d = 0; d < 16; ++d) s_acc[d] *= 0.1f;
    }
    if (valid) {
#if defined(__HIP_DEVICE_COMPILE__)
        #pragma unroll
        for (int d = 0; d < 16; ++d)
            unsafeAtomicAdd(&s_atomic[((size_t)b * 10 + c) * 16 + d], s_acc[d]);
#endif
    }
}

extern "C" void kernel_launch(void* const* d_in, const int* in_sizes, int n_in,
                              void* d_out, int out_size, void* d_ws, size_t ws_size,
                              hipStream_t stream)
{
    const float* u = (const float*)d_in[0];   // [512,1152,8]
    const float* W = (const float*)d_in[1];   // [1152,10,16,8]
    float* out = (float*)d_out;               // [512,10,16]

    float* v0 = (float*)d_ws;
    float* v1 = v0 + 81920;
    float* s0 = v1 + 81920;
    float* s1 = s0 + 81920;
    float* s2 = s1 + 81920;
    float* wt = s2 + 81920;                   // 1,474,560 f32 (5.9 MB)

    const size_t head   = (size_t)5 * 81920 * sizeof(float);          // 1.64 MB
    const size_t wtsz   = (size_t)1152 * 1280 * sizeof(float);        // 5.90 MB
    const size_t uh_b16 = (size_t)512 * 1152 * 160 * 2;               // 188.7 MB

    dim3 blk(256);

    if (ws_size >= head + wtsz + uh_b16) {
        unsigned short* uhh = (unsigned short*)(wt + 1152 * 1280);
        // transpose_W also zeroes s0..s2 (61440 float4) - no separate memset
        transpose_W<<<1440, blk, 0, stream>>>((const float4*)W, (float4*)wt,
                                              (float4*)s0);
        produce_uhat_t<<<2048, blk, 0, stream>>>(u, wt, uhh, s0);
        route6s<1><<<2048, blk, 0, stream>>>(uhh, s0, nullptr, s1);
        route6s<2><<<2048, blk, 0, stream>>>(uhh, s0, s1, s2);
        squash_scale<<<20, blk, 0, stream>>>(s2, out, 1.0f);
    } else if (ws_size >= head + uh_b16) {
        hipMemsetAsync(s0, 0, (size_t)3 * 81920 * sizeof(float), stream);
        unsigned short* uhh = (unsigned short*)wt;   // no W_t buffer
        produce_uhat_div<<<1024, blk, 0, stream>>>(u, W, uhh, s0);
        route6s<1><<<2048, blk, 0, stream>>>(uhh, s0, nullptr, s1);
        route6s<2><<<2048, blk, 0, stream>>>(uhh, s0, s1, s2);
        squash_scale<<<20, blk, 0, stream>>>(s2, out, 1.0f);
    } else {
        hipMemsetAsync(s0, 0, (size_t)3 * 81920 * sizeof(float), stream);
        dim3 grid(48, 22);
        pass_fb<0><<<grid, blk, 0, stream>>>(u, W, nullptr, nullptr, s0);
        squash_scale<<<20, blk, 0, stream>>>(s0, v0, 1.0f);
        pass_fb<1><<<grid, blk, 0, stream>>>(u, W, v0, nullptr, s1);
        squash_scale<<<20, blk, 0, stream>>>(s1, v1, 1.0f);
        pass_fb<2><<<grid, blk, 0, stream>>>(u, W, v0, v1, s2);
        squash_scale<<<20, blk, 0, stream>>>(s2, out, 1.0f);
    }
}